// Round 1
// baseline (860.669 us; speedup 1.0000x reference)
//
#include <hip/hip_runtime.h>
#include <hip/hip_bf16.h>

// Problem dims (fixed): T=1024, B=32, DIN=256, H=256, AA=21, L=2
#define T_DIM 1024
#define B_DIM 32
#define DIN_DIM 256
#define H_DIM 256
#define AA_DIM 21
#define M_ROWS (B_DIM * T_DIM)   // 32768 rows, row index = b*T + t everywhere

typedef __attribute__((ext_vector_type(8))) short bf16x8;   // 8 bf16 = 4 VGPRs
typedef __attribute__((ext_vector_type(4))) float f32x4;

typedef __attribute__((address_space(3))) void lds_void;
typedef const __attribute__((address_space(1))) void glb_void;

__device__ __forceinline__ void gload_lds16(const void* g, void* l) {
    // per-lane 16B global gather -> LDS at (wave-uniform base + lane*16)
    __builtin_amdgcn_global_load_lds((glb_void*)g, (lds_void*)l, 16, 0, 0);
}

__device__ __forceinline__ float b2f(short v) {
    unsigned u = ((unsigned)(unsigned short)v) << 16;
    float f;
    __builtin_memcpy(&f, &u, 4);
    return f;
}

// ---------------------------------------------------------------------------
// f32 -> bf16 convert
__global__ __launch_bounds__(256) void cvt_bf16(const float* __restrict__ s,
                                                __hip_bfloat16* __restrict__ d, int n) {
    int i = blockIdx.x * 256 + threadIdx.x;
    if (i < n) d[i] = __float2bfloat16(s[i]);
}

// f32 (K,N) -> bf16 (N,K) transpose+convert (weights, small)
__global__ __launch_bounds__(256) void cvt_t_bf16(const float* __restrict__ s,
                                                  __hip_bfloat16* __restrict__ d,
                                                  int K, int N) {
    int i = blockIdx.x * 256 + threadIdx.x;
    if (i < K * N) {
        int k = i / N, n = i - k * N;
        d[(long)n * K + k] = __float2bfloat16(s[i]);
    }
}

// ---------------------------------------------------------------------------
// bf16 GEMM: C(M,N) = A(M,K) * Bt(N,K)^T  [+ bias], C stored bf16.
// m97 structure: 128x128 tile, 4 waves 2x2, each wave 64x64 via 4x4 mfma
// 16x16x32 tiles, BK=32, global_load_lds width-16 staging for both A and B.
__global__ __launch_bounds__(256) void gemm_bf16(
    const __hip_bfloat16* __restrict__ A,
    const __hip_bfloat16* __restrict__ Bt,
    const float* __restrict__ bias,   // len N or nullptr
    __hip_bfloat16* __restrict__ C,
    int M, int N, int K)
{
    __shared__ __align__(16) __hip_bfloat16 sm[8192]; // A tile [0,4096), B tile [4096,8192)
    const int tid  = threadIdx.x;
    const int lane = tid & 63;
    const int wave = tid >> 6;
    const int wm = wave & 1;       // wave row (0..1)
    const int wn = wave >> 1;      // wave col (0..1)
    const long m0 = (long)blockIdx.x * 128;
    const long n0 = (long)blockIdx.y * 128;

    f32x4 acc[4][4] = {};

    const int ldrow = lane >> 2;       // 0..15 row within 16-row chunk
    const int ldk   = (lane & 3) * 8;  // k-element offset 0,8,16,24

    for (int kb = 0; kb < K; kb += 32) {
        __syncthreads();  // previous compute done before overwriting LDS
#pragma unroll
        for (int i = 0; i < 2; ++i) {
            const int chunk = wave * 2 + i;           // 0..7 -> rows chunk*16..+15
            const int row = chunk * 16 + ldrow;
            gload_lds16(A  + (m0 + row) * (long)K + kb + ldk, sm + chunk * 512);
            gload_lds16(Bt + (n0 + row) * (long)K + kb + ldk, sm + 4096 + chunk * 512);
        }
        __syncthreads();  // drains vmcnt(0): staged data visible

        bf16x8 af[4], bfv[4];
        const int fr = lane & 15;
        const int fq = (lane >> 4) * 8;   // k base 0,8,16,24
#pragma unroll
        for (int i = 0; i < 4; ++i) {
            af[i]  = *(const bf16x8*)(sm + (wm * 64 + i * 16 + fr) * 32 + fq);
            bfv[i] = *(const bf16x8*)(sm + 4096 + (wn * 64 + i * 16 + fr) * 32 + fq);
        }
#pragma unroll
        for (int i = 0; i < 4; ++i)
#pragma unroll
            for (int j = 0; j < 4; ++j)
                acc[i][j] = __builtin_amdgcn_mfma_f32_16x16x32_bf16(
                    af[i], bfv[j], acc[i][j], 0, 0, 0);
    }

    // epilogue: C/D layout col=lane&15, row=(lane>>4)*4+reg  [m89/m91 verified]
    const int col_l = lane & 15;
    const int row_l = (lane >> 4) * 4;
#pragma unroll
    for (int j = 0; j < 4; ++j) {
        const long gc = n0 + wn * 64 + j * 16 + col_l;
        const float bv = bias ? bias[gc] : 0.0f;
#pragma unroll
        for (int i = 0; i < 4; ++i) {
            const long gr = m0 + wm * 64 + i * 16 + row_l;
#pragma unroll
            for (int r = 0; r < 4; ++r)
                C[(gr + r) * (long)N + gc] = __float2bfloat16(acc[i][j][r] + bv);
        }
    }
}

// ---------------------------------------------------------------------------
// SRU scan, one thread per (dir, b, h) recurrence; 16384 threads total.
// U: (M_ROWS, 2048) bf16, col = dir*1024 + k*256 + h, chunks k = [cand,forget,reset,highway]
// hout: (M_ROWS, 512) bf16, col = dir*256 + h
__global__ __launch_bounds__(64) void sru_scan(
    const __hip_bfloat16* __restrict__ U,
    const float* __restrict__ wc,    // (2,2,H): [dir][vf,vr][h]
    const float* __restrict__ bias,  // (2,2,H): [dir][bf,br][h]
    __hip_bfloat16* __restrict__ hout)
{
    const int id  = blockIdx.x * 64 + threadIdx.x;  // 0..16383
    const int dir = id >> 13;                       // B*H = 8192
    const int rem = id & 8191;
    const int b   = rem >> 8;
    const int h   = rem & 255;

    const float vf = wc[(dir * 2 + 0) * H_DIM + h];
    const float vr = wc[(dir * 2 + 1) * H_DIM + h];
    const float bf = bias[(dir * 2 + 0) * H_DIM + h];
    const float br = bias[(dir * 2 + 1) * H_DIM + h];

    const long colbase = dir * 1024 + h;
    float c = 0.0f;
    for (int s = 0; s < T_DIM; ++s) {
        const int t = dir ? (T_DIM - 1 - s) : s;
        const long row = (long)(b * T_DIM + t);
        const long rb = row * 2048 + colbase;
        const float u0 = __bfloat162float(U[rb]);
        const float u1 = __bfloat162float(U[rb + 256]);
        const float u2 = __bfloat162float(U[rb + 512]);
        const float u3 = __bfloat162float(U[rb + 768]);
        const float f  = 1.0f / (1.0f + __expf(-(u1 + vf * c + bf)));
        const float c2 = f * (c - u0) + u0;             // f*c + (1-f)*u0
        const float r  = 1.0f / (1.0f + __expf(-(u2 + vr * c + br)));  // uses OLD c
        const float hv = r * (c2 - u3) + u3;            // r*c2 + (1-r)*u3
        c = c2;
        hout[row * 512 + dir * 256 + h] = __float2bfloat16(hv);
    }
}

// ---------------------------------------------------------------------------
// logits (N=21, K=256) + log_softmax, one thread per row.
// lp_w addresses are wave-uniform -> scalar loads; lp_w is 21KB, L1-resident.
__global__ __launch_bounds__(256) void logits_lsm(
    const __hip_bfloat16* __restrict__ fc,   // (M_ROWS, 256) bf16
    const float* __restrict__ lpw,           // (21, 256) f32
    const float* __restrict__ lpb,           // (21,) f32
    float* __restrict__ out, int rows)
{
    const int row = blockIdx.x * 256 + threadIdx.x;
    if (row >= rows) return;
    float acc[AA_DIM];
#pragma unroll
    for (int a = 0; a < AA_DIM; ++a) acc[a] = lpb[a];
    const __hip_bfloat16* hr = fc + (long)row * H_DIM;
    for (int k = 0; k < H_DIM; k += 8) {
        bf16x8 raw = *(const bf16x8*)(hr + k);
#pragma unroll
        for (int j = 0; j < 8; ++j) {
            const float hvj = b2f(raw[j]);
#pragma unroll
            for (int a = 0; a < AA_DIM; ++a)
                acc[a] += hvj * lpw[a * H_DIM + k + j];
        }
    }
    float m = acc[0];
#pragma unroll
    for (int a = 1; a < AA_DIM; ++a) m = fmaxf(m, acc[a]);
    float s = 0.0f;
#pragma unroll
    for (int a = 0; a < AA_DIM; ++a) s += __expf(acc[a] - m);
    const float lse = __logf(s) + m;
#pragma unroll
    for (int a = 0; a < AA_DIM; ++a) out[(long)row * AA_DIM + a] = acc[a] - lse;
}

// ---------------------------------------------------------------------------
extern "C" void kernel_launch(void* const* d_in, const int* in_sizes, int n_in,
                              void* d_out, int out_size, void* d_ws, size_t ws_size,
                              hipStream_t stream)
{
    const float* x     = (const float*)d_in[0];
    // d_in[1] = hidden, unused (as in reference)
    const float* w_l0  = (const float*)d_in[2];
    const float* wc_l0 = (const float*)d_in[3];
    const float* b_l0  = (const float*)d_in[4];
    const float* w_l1  = (const float*)d_in[5];
    const float* wc_l1 = (const float*)d_in[6];
    const float* b_l1  = (const float*)d_in[7];
    const float* fc1_w = (const float*)d_in[8];
    const float* fc1_b = (const float*)d_in[9];
    const float* lp_w  = (const float*)d_in[10];
    const float* lp_b  = (const float*)d_in[11];
    float* out = (float*)d_out;

    // Workspace layout (~211 MiB total):
    char* ws = (char*)d_ws;
    __hip_bfloat16* U      = (__hip_bfloat16*)(ws);              // 134,217,728 B (reused L0+L1)
    __hip_bfloat16* h0b    = (__hip_bfloat16*)(ws + 134217728);  //  33,554,432
    __hip_bfloat16* h1b    = (__hip_bfloat16*)(ws + 167772160);  //  33,554,432
    __hip_bfloat16* xb     = (__hip_bfloat16*)(ws + 201326592);  //  16,777,216
    __hip_bfloat16* fcob   = xb;                                 //  alias: xb dead after GEMM0
    __hip_bfloat16* w0t    = (__hip_bfloat16*)(ws + 218103808);  //   1,048,576  (2048,256)
    __hip_bfloat16* w1t    = (__hip_bfloat16*)(ws + 219152384);  //   2,097,152  (2048,512)
    __hip_bfloat16* fc1wb  = (__hip_bfloat16*)(ws + 221249536);  //     262,144  (256,512)

    // 1) converts (x is (B,T,DIN): row index b*T+t matches M ordering everywhere)
    cvt_bf16<<<(M_ROWS * DIN_DIM + 255) / 256, 256, 0, stream>>>(x, xb, M_ROWS * DIN_DIM);
    cvt_t_bf16<<<(DIN_DIM * 2048 + 255) / 256, 256, 0, stream>>>(w_l0, w0t, DIN_DIM, 2048);
    cvt_t_bf16<<<(512 * 2048 + 255) / 256, 256, 0, stream>>>(w_l1, w1t, 512, 2048);
    cvt_bf16<<<(H_DIM * 512 + 255) / 256, 256, 0, stream>>>(fc1_w, fc1wb, H_DIM * 512); // already (N,K)

    // 2) U0 = xb (32768,256) x w0t^T -> (32768,2048)
    gemm_bf16<<<dim3(M_ROWS / 128, 2048 / 128), 256, 0, stream>>>(
        xb, w0t, nullptr, U, M_ROWS, 2048, DIN_DIM);
    // 3) SRU layer 0 scan -> h0b (32768,512)
    sru_scan<<<256, 64, 0, stream>>>(U, wc_l0, b_l0, h0b);
    // 4) U1 = h0b (32768,512) x w1t^T -> (32768,2048)
    gemm_bf16<<<dim3(M_ROWS / 128, 2048 / 128), 256, 0, stream>>>(
        h0b, w1t, nullptr, U, M_ROWS, 2048, 512);
    // 5) SRU layer 1 scan -> h1b
    sru_scan<<<256, 64, 0, stream>>>(U, wc_l1, b_l1, h1b);
    // 6) fc = h1b (32768,512) x fc1_w^T + fc1_b -> (32768,256) bf16
    gemm_bf16<<<dim3(M_ROWS / 128, 256 / 128), 256, 0, stream>>>(
        h1b, fc1wb, fc1_b, fcob, M_ROWS, 256, 512);
    // 7) logits + log_softmax -> out (B,T,21)
    logits_lsm<<<M_ROWS / 256, 256, 0, stream>>>(fcob, lp_w, lp_b, out, M_ROWS);
}

// Round 2
// 648.278 us; speedup vs baseline: 1.3276x; 1.3276x over previous
//
#include <hip/hip_runtime.h>
#include <hip/hip_bf16.h>

// Problem dims (fixed): T=1024, B=32, DIN=256, H=256, AA=21, L=2
#define T_DIM 1024
#define B_DIM 32
#define DIN_DIM 256
#define H_DIM 256
#define AA_DIM 21
#define M_ROWS (B_DIM * T_DIM)   // 32768 rows, row index = b*T + t everywhere

typedef __attribute__((ext_vector_type(8))) short bf16x8;   // 8 bf16 = 4 VGPRs
typedef __attribute__((ext_vector_type(4))) float f32x4;

typedef __attribute__((address_space(3))) void lds_void;
typedef const __attribute__((address_space(1))) void glb_void;

__device__ __forceinline__ void gload_lds16(const void* g, void* l) {
    __builtin_amdgcn_global_load_lds((glb_void*)g, (lds_void*)l, 16, 0, 0);
}

__device__ __forceinline__ float b2f(unsigned short v) {
    unsigned u = ((unsigned)v) << 16;
    float f;
    __builtin_memcpy(&f, &u, 4);
    return f;
}

// ---------------------------------------------------------------------------
// f32 -> bf16 convert
__global__ __launch_bounds__(256) void cvt_bf16(const float* __restrict__ s,
                                                __hip_bfloat16* __restrict__ d, int n) {
    int i = blockIdx.x * 256 + threadIdx.x;
    if (i < n) d[i] = __float2bfloat16(s[i]);
}

// SRU weight: f32 (K, 2, 4, H) -> bf16 (N=2048, K) transposed with INTERLEAVED
// row order: n = dir*1024 + h*4 + k  (so GEMM output U has the 4 gates of one
// (dir,h) adjacent -> scan does ONE 8B load per timestep)
__global__ __launch_bounds__(256) void cvt_w_sru(const float* __restrict__ s,
                                                 __hip_bfloat16* __restrict__ d,
                                                 int K) {
    int i = blockIdx.x * 256 + threadIdx.x;
    if (i >= K * 2048) return;
    // input flat: ((kk*2 + dir)*4 + k)*H + h
    int kk  = i >> 11;          // / 2048
    int rem = i & 2047;
    int dir = rem >> 10;
    int k   = (rem >> 8) & 3;
    int h   = rem & 255;
    int n   = dir * 1024 + h * 4 + k;
    d[(long)n * K + kk] = __float2bfloat16(s[i]);
}

// f32 (N,K) row-major -> bf16 (N,K) (fc1_w is already (N,K))
// handled by cvt_bf16.

// ---------------------------------------------------------------------------
// bf16 GEMM: C(M,N) = A(M,K) * Bt(N,K)^T  [+ bias], C stored bf16.
__global__ __launch_bounds__(256) void gemm_bf16(
    const __hip_bfloat16* __restrict__ A,
    const __hip_bfloat16* __restrict__ Bt,
    const float* __restrict__ bias,   // len N or nullptr
    __hip_bfloat16* __restrict__ C,
    int M, int N, int K)
{
    __shared__ __align__(16) __hip_bfloat16 sm[8192]; // A tile [0,4096), B tile [4096,8192)
    const int tid  = threadIdx.x;
    const int lane = tid & 63;
    const int wave = tid >> 6;
    const int wm = wave & 1;
    const int wn = wave >> 1;
    const long m0 = (long)blockIdx.x * 128;
    const long n0 = (long)blockIdx.y * 128;

    f32x4 acc[4][4] = {};

    const int ldrow = lane >> 2;
    const int ldk   = (lane & 3) * 8;

    for (int kb = 0; kb < K; kb += 32) {
        __syncthreads();
#pragma unroll
        for (int i = 0; i < 2; ++i) {
            const int chunk = wave * 2 + i;
            const int row = chunk * 16 + ldrow;
            gload_lds16(A  + (m0 + row) * (long)K + kb + ldk, sm + chunk * 512);
            gload_lds16(Bt + (n0 + row) * (long)K + kb + ldk, sm + 4096 + chunk * 512);
        }
        __syncthreads();

        bf16x8 af[4], bfv[4];
        const int fr = lane & 15;
        const int fq = (lane >> 4) * 8;
#pragma unroll
        for (int i = 0; i < 4; ++i) {
            af[i]  = *(const bf16x8*)(sm + (wm * 64 + i * 16 + fr) * 32 + fq);
            bfv[i] = *(const bf16x8*)(sm + 4096 + (wn * 64 + i * 16 + fr) * 32 + fq);
        }
#pragma unroll
        for (int i = 0; i < 4; ++i)
#pragma unroll
            for (int j = 0; j < 4; ++j)
                acc[i][j] = __builtin_amdgcn_mfma_f32_16x16x32_bf16(
                    af[i], bfv[j], acc[i][j], 0, 0, 0);
    }

    const int col_l = lane & 15;
    const int row_l = (lane >> 4) * 4;
#pragma unroll
    for (int j = 0; j < 4; ++j) {
        const long gc = n0 + wn * 64 + j * 16 + col_l;
        const float bv = bias ? bias[gc] : 0.0f;
#pragma unroll
        for (int i = 0; i < 4; ++i) {
            const long gr = m0 + wm * 64 + i * 16 + row_l;
#pragma unroll
            for (int r = 0; r < 4; ++r)
                C[(gr + r) * (long)N + gc] = __float2bfloat16(acc[i][j][r] + bv);
        }
    }
}

// ---------------------------------------------------------------------------
// SRU scan, one thread per (dir, b, h) recurrence; 16384 threads = 1 wave/CU.
// U layout INTERLEAVED: col = dir*1024 + h*4 + k, so one ushort4 (8B) load per
// step. Depth-16 register ring of prefetched loads -> throughput-bound instead
// of latency-bound (addresses are data-independent).
#define SCAN_PF 16
__global__ __launch_bounds__(64) void sru_scan(
    const __hip_bfloat16* __restrict__ U,
    const float* __restrict__ wc,    // (2,2,H): [dir][vf,vr][h]
    const float* __restrict__ bias,  // (2,2,H): [dir][bf,br][h]
    __hip_bfloat16* __restrict__ hout)
{
    const int id  = blockIdx.x * 64 + threadIdx.x;  // 0..16383
    const int dir = id >> 13;                       // B*H = 8192
    const int rem = id & 8191;
    const int b   = rem >> 8;
    const int h   = rem & 255;

    const float vf = wc[(dir * 2 + 0) * H_DIM + h];
    const float vr = wc[(dir * 2 + 1) * H_DIM + h];
    const float bf = bias[(dir * 2 + 0) * H_DIM + h];
    const float br = bias[(dir * 2 + 1) * H_DIM + h];

    // pointer for step s: U + row(s)*2048 + dir*1024 + h*4, row = b*T + t(s)
    // dir==0: t=s (row steps +1 -> +2048 elems); dir==1: t=T-1-s (row steps -1)
    const long row0  = (long)b * T_DIM + (dir ? (T_DIM - 1) : 0);
    const long rstep = dir ? -2048 : 2048;
    const ushort4* p = (const ushort4*)(U + row0 * 2048 + dir * 1024 + (h << 2));
    const long pstep = rstep / 4;           // ushort4 units

    __hip_bfloat16* ho = hout + row0 * 512 + dir * 256 + h;
    const long hstep = dir ? -512 : 512;

    ushort4 buf[SCAN_PF];
#pragma unroll
    for (int j = 0; j < SCAN_PF; ++j) buf[j] = p[j * pstep];

    float c = 0.0f;
    for (int s0 = 0; s0 < T_DIM; s0 += SCAN_PF) {
#pragma unroll
        for (int j = 0; j < SCAN_PF; ++j) {
            const ushort4 u = buf[j];
            const int sp = s0 + j + SCAN_PF;
            if (sp < T_DIM) buf[j] = p[(long)sp * pstep];
            const float u0 = b2f(u.x);   // candidate
            const float u1 = b2f(u.y);   // forget
            const float u2 = b2f(u.z);   // reset
            const float u3 = b2f(u.w);   // highway
            const float f  = 1.0f / (1.0f + __expf(-(u1 + vf * c + bf)));
            const float c2 = f * (c - u0) + u0;
            const float r  = 1.0f / (1.0f + __expf(-(u2 + vr * c + br)));  // OLD c
            const float hv = r * (c2 - u3) + u3;
            c = c2;
            ho[(long)(s0 + j) * hstep] = __float2bfloat16(hv);
        }
    }
}

// ---------------------------------------------------------------------------
// logits (N=21, K=256) + log_softmax, one thread per row.
__global__ __launch_bounds__(256) void logits_lsm(
    const __hip_bfloat16* __restrict__ fc,   // (M_ROWS, 256) bf16
    const float* __restrict__ lpw,           // (21, 256) f32
    const float* __restrict__ lpb,           // (21,) f32
    float* __restrict__ out, int rows)
{
    const int row = blockIdx.x * 256 + threadIdx.x;
    if (row >= rows) return;
    float acc[AA_DIM];
#pragma unroll
    for (int a = 0; a < AA_DIM; ++a) acc[a] = lpb[a];
    const __hip_bfloat16* hr = fc + (long)row * H_DIM;
    for (int k = 0; k < H_DIM; k += 8) {
        bf16x8 raw = *(const bf16x8*)(hr + k);
#pragma unroll
        for (int j = 0; j < 8; ++j) {
            const float hvj = b2f((unsigned short)raw[j]);
#pragma unroll
            for (int a = 0; a < AA_DIM; ++a)
                acc[a] += hvj * lpw[a * H_DIM + k + j];
        }
    }
    float m = acc[0];
#pragma unroll
    for (int a = 1; a < AA_DIM; ++a) m = fmaxf(m, acc[a]);
    float s = 0.0f;
#pragma unroll
    for (int a = 0; a < AA_DIM; ++a) s += __expf(acc[a] - m);
    const float lse = __logf(s) + m;
#pragma unroll
    for (int a = 0; a < AA_DIM; ++a) out[(long)row * AA_DIM + a] = acc[a] - lse;
}

// ---------------------------------------------------------------------------
extern "C" void kernel_launch(void* const* d_in, const int* in_sizes, int n_in,
                              void* d_out, int out_size, void* d_ws, size_t ws_size,
                              hipStream_t stream)
{
    const float* x     = (const float*)d_in[0];
    const float* w_l0  = (const float*)d_in[2];
    const float* wc_l0 = (const float*)d_in[3];
    const float* b_l0  = (const float*)d_in[4];
    const float* w_l1  = (const float*)d_in[5];
    const float* wc_l1 = (const float*)d_in[6];
    const float* b_l1  = (const float*)d_in[7];
    const float* fc1_w = (const float*)d_in[8];
    const float* fc1_b = (const float*)d_in[9];
    const float* lp_w  = (const float*)d_in[10];
    const float* lp_b  = (const float*)d_in[11];
    float* out = (float*)d_out;

    char* ws = (char*)d_ws;
    __hip_bfloat16* U      = (__hip_bfloat16*)(ws);              // 134,217,728 B
    __hip_bfloat16* h0b    = (__hip_bfloat16*)(ws + 134217728);  //  33,554,432
    __hip_bfloat16* h1b    = (__hip_bfloat16*)(ws + 167772160);  //  33,554,432
    __hip_bfloat16* xb     = (__hip_bfloat16*)(ws + 201326592);  //  16,777,216
    __hip_bfloat16* fcob   = xb;                                 //  alias after GEMM0
    __hip_bfloat16* w0t    = (__hip_bfloat16*)(ws + 218103808);  //  (2048,256)
    __hip_bfloat16* w1t    = (__hip_bfloat16*)(ws + 219152384);  //  (2048,512)
    __hip_bfloat16* fc1wb  = (__hip_bfloat16*)(ws + 221249536);  //  (256,512)

    cvt_bf16<<<(M_ROWS * DIN_DIM + 255) / 256, 256, 0, stream>>>(x, xb, M_ROWS * DIN_DIM);
    cvt_w_sru<<<(DIN_DIM * 2048 + 255) / 256, 256, 0, stream>>>(w_l0, w0t, DIN_DIM);
    cvt_w_sru<<<(512 * 2048 + 255) / 256, 256, 0, stream>>>(w_l1, w1t, 512);
    cvt_bf16<<<(H_DIM * 512 + 255) / 256, 256, 0, stream>>>(fc1_w, fc1wb, H_DIM * 512);

    gemm_bf16<<<dim3(M_ROWS / 128, 2048 / 128), 256, 0, stream>>>(
        xb, w0t, nullptr, U, M_ROWS, 2048, DIN_DIM);
    sru_scan<<<256, 64, 0, stream>>>(U, wc_l0, b_l0, h0b);
    gemm_bf16<<<dim3(M_ROWS / 128, 2048 / 128), 256, 0, stream>>>(
        h0b, w1t, nullptr, U, M_ROWS, 2048, 512);
    sru_scan<<<256, 64, 0, stream>>>(U, wc_l1, b_l1, h1b);
    gemm_bf16<<<dim3(M_ROWS / 128, 256 / 128), 256, 0, stream>>>(
        h1b, fc1wb, fc1_b, fcob, M_ROWS, 256, 512);
    logits_lsm<<<M_ROWS / 256, 256, 0, stream>>>(fcob, lp_w, lp_b, out, M_ROWS);
}